// Round 9
// baseline (641.162 us; speedup 1.0000x reference)
//
#include <hip/hip_runtime.h>
#include <hip/hip_bf16.h>

#define D 128
#define EPS 1e-5f
#define SCAP 32   // per-group compaction chunk in k_sim
#define GB 10     // gather batch (rows in flight per group)

// ---------- fused: edge count (atomics) + input-x row norms ----------
__global__ __launch_bounds__(256) void k_pre(
    const int* __restrict__ row, int* __restrict__ cnt, int E,
    const float* __restrict__ h, float* __restrict__ nrm, int N, int cB) {
  if ((int)blockIdx.x < cB) {
    int e = blockIdx.x * 256 + threadIdx.x;
    if (e < E) atomicAdd(&cnt[row[e]], 1);
  } else {
    int i = (blockIdx.x - cB) * 8 + (threadIdx.x >> 5);
    int sub = threadIdx.x & 31;
    if (i >= N) return;
    float4 a = ((const float4*)(h + (size_t)i * D))[sub];
    float v = a.x * a.x + a.y * a.y + a.z * a.z + a.w * a.w;
    for (int off = 16; off > 0; off >>= 1) v += __shfl_down(v, off, 32);
    if (sub == 0) nrm[i] = sqrtf(v);
  }
}

// ---------- single-block scan: cnt -> rptr (replaces bsum/bscan/apply) ----
// C = ints per thread = 4*nb; NpadS = 1024*nb = 256*C exactly.
__global__ __launch_bounds__(256) void k_scan(const int* __restrict__ cnt,
                                              int* __restrict__ rptr,
                                              int N, int E, int C) {
  __shared__ int sh[256];
  int t = threadIdx.x;
  int base = t * C;
  int s = 0;
  for (int j = 0; j < C; j += 4) {
    int4 c4 = ((const int4*)(cnt + base + j))[0];
    s += c4.x + c4.y + c4.z + c4.w;
  }
  sh[t] = s;
  __syncthreads();
  for (int off = 1; off < 256; off <<= 1) {
    int u = (t >= off) ? sh[t - off] : 0;
    __syncthreads();
    sh[t] += u;
    __syncthreads();
  }
  int run = sh[t] - s;                 // exclusive prefix of this thread
  for (int j = 0; j < C; j += 4) {
    int4 c4 = ((const int4*)(cnt + base + j))[0];
    int i0 = base + j;
    if (i0 + 0 < N) rptr[i0 + 0] = run;  run += c4.x;
    if (i0 + 1 < N) rptr[i0 + 1] = run;  run += c4.y;
    if (i0 + 2 < N) rptr[i0 + 2] = run;  run += c4.z;
    if (i0 + 3 < N) rptr[i0 + 3] = run;  run += c4.w;
  }
  if (t == 0) rptr[N] = E;
}

// ---------- two-phase bucket placement ----------
// Pass A: 4-row buckets (chain = ~64 atomics/counter ~ 11 us; write frontier
// ~12.5K hot lines, L2-resident). Packed pair: (row&127)<<25 | col.
__global__ __launch_bounds__(256) void k_bktA(
    const int* __restrict__ row, const int* __restrict__ col,
    const int* __restrict__ rptr, int* __restrict__ bcur,
    unsigned* __restrict__ pairs, int E) {
  int e = blockIdx.x * 256 + threadIdx.x;
  if (e < E) {
    int r = row[e];
    int b = r >> 2;
    int q = rptr[b << 2] + atomicAdd(&bcur[b], 1);
    pairs[q] = ((unsigned)(r & 127) << 25) | (unsigned)col[e];
  }
}

// Pass B: one block per 128 rows (32 buckets); LDS cursors place pairs into
// final CSR slots; output window contiguous ~8KB -> hot L2 lines.
__global__ __launch_bounds__(256) void k_bktB(
    const unsigned* __restrict__ pairs, const int* __restrict__ rptr,
    int* __restrict__ colS, int N) {
  __shared__ int curL[128];
  int b = blockIdx.x;
  int r0 = b << 7;
  int rend = min(r0 + 128, N);
  int q0 = rptr[r0], q1 = rptr[rend];
  if (threadIdx.x < 128) curL[threadIdx.x] = 0;
  __syncthreads();
  for (int q = q0 + threadIdx.x; q < q1; q += 256) {
    unsigned pk = pairs[q];
    int lr = pk >> 25;
    int c = (int)(pk & 0x1FFFFFFu);
    int p = rptr[r0 + lr] + atomicAdd(&curL[lr], 1);
    colS[p] = c;
  }
}

// node-centric reverse-edge lookup: group of 32 lanes per node i; lane's
// edge p -> search i in c's adjacency list.
__global__ __launch_bounds__(256) void k_rev(const int* __restrict__ colS,
                                             const int* __restrict__ rptr,
                                             int* __restrict__ rev, int N) {
  int grp = threadIdx.x >> 5, sub = threadIdx.x & 31;
  int i = blockIdx.x * 8 + grp;
  if (i >= N) return;
  int p0 = rptr[i], p1 = rptr[i + 1];
  for (int p = p0 + sub; p < p1; p += 32) {
    int c = colS[p];
    int q1 = rptr[c + 1];
    int rv = -1;
    for (int q = rptr[c]; q < q1; ++q)
      if (colS[q] == i) { rv = q; break; }
    rev[p] = rv;
  }
}

// ---------- sim: one dot per undirected pair; owner rule handles truncation.
// Node i computes edge p=(i->c) iff (c > i) || (rev[p] < 0). When rev exists
// the bitwise-identical value is scattered to both directions.
__global__ __launch_bounds__(256) void k_sim(
    const float* __restrict__ h, const float* __restrict__ nrm,
    const int* __restrict__ rptr, const int* __restrict__ colS,
    const int* __restrict__ rev, float* __restrict__ simS, int N) {
  __shared__ int cL[8 * SCAP];
  __shared__ int pL[8 * SCAP];
  __shared__ int rL[8 * SCAP];
  __shared__ float nL[8 * SCAP];
  int grp = threadIdx.x >> 5;          // 8 groups of 32 lanes
  int sub = threadIdx.x & 31;
  int half = grp & 1;                  // lane 0-31 vs 32-63 within wave64
  int i = blockIdx.x * 8 + grp;
  if (i >= N) return;
  int gb = grp * SCAP;
  int p0 = rptr[i], p1 = rptr[i + 1];
  float4 ai = ((const float4*)(h + (size_t)i * D))[sub];
  float ni = nrm[i];
  for (int base = p0; base < p1; base += SCAP) {
    int p = base + sub;
    bool inr = p < p1;
    int c = inr ? colS[p] : 0;
    int rv = inr ? rev[p] : 0;
    bool ok = inr && (c > i || rv < 0);   // ownership rule
    unsigned long long mb = __ballot(ok);
    unsigned mh = (unsigned)(mb >> (half * 32));
    int pos = __popc(mh & ((1u << sub) - 1u));
    int K = __popc(mh);
    if (ok) {
      cL[gb + pos] = c;
      pL[gb + pos] = p;
      rL[gb + pos] = rv;
      nL[gb + pos] = nrm[c];
    }
    __builtin_amdgcn_wave_barrier();
    for (int j0 = 0; j0 < K; j0 += GB) {
      int cc_[GB];
      bool vv[GB];
      float4 b[GB];
#pragma unroll
      for (int k = 0; k < GB; ++k) {
        int idx = j0 + k;
        vv[k] = idx < K;
        cc_[k] = vv[k] ? cL[gb + idx] : i;
      }
#pragma unroll
      for (int k = 0; k < GB; ++k)
        b[k] = ((const float4*)(h + (size_t)cc_[k] * D))[sub];
#pragma unroll
      for (int k = 0; k < GB; ++k) {
        float v = ai.x * b[k].x + ai.y * b[k].y + ai.z * b[k].z + ai.w * b[k].w;
        for (int off = 16; off > 0; off >>= 1) v += __shfl_down(v, off, 32);
        if (sub == 0 && vv[k]) {
          int idx = j0 + k;
          float sm = v / (ni * nL[gb + idx]);
          sm = (sm < 0.1f) ? 0.0f : sm;
          simS[pL[gb + idx]] = sm;       // this direction
          int rv2 = rL[gb + idx];
          if (rv2 >= 0) simS[rv2] = sm;  // reverse direction (bitwise equal)
        }
      }
    }
    __builtin_amdgcn_wave_barrier();   // LDS reused next chunk
  }
}

// ---------- fused role-split: gemm (S = h@W) + rs (row l1 norms) ----------
// gemm blocks [0, nG), rs blocks [nG, nG+nRs). Union footprint = gemm's own
// (rs adds no LDS/arrays) -> safe pairing per the round-4/6 lesson; all 978
// blocks co-resident so rs rides free under gemm.
__global__ __launch_bounds__(256) void k_gemmrs(
    const float* __restrict__ h, const float* __restrict__ W,
    float* __restrict__ S, const float* __restrict__ simS,
    const int* __restrict__ rptr, float* __restrict__ rsE, int N, int nG) {
  __shared__ float Ws[64 * D];         // 32 KB (gemm role only)
  if ((int)blockIdx.x >= nG) {
    // ---- rs role: identical math/order to the old k_rs ----
    int i = ((int)blockIdx.x - nG) * 256 + threadIdx.x;
    if (i >= N) return;
    int p1 = rptr[i + 1];
    float rs = 0.f;
    for (int p = rptr[i]; p < p1; ++p) rs += simS[p];
    rsE[i] = (rs > 0.f) ? rs : 1.f;
    return;
  }
  int t = threadIdx.x;
  int i0 = (int)blockIdx.x * 64;
  int tx = t & 15, ty = t >> 4;        // rows 4ty..4ty+3, cols 4tx & 64+4tx
  int gi[4];
  bool vld[4];
#pragma unroll
  for (int r = 0; r < 4; ++r) {
    gi[r] = i0 + ty * 4 + r;
    vld[r] = gi[r] < N;
  }
  float acc[4][8] = {};
  for (int ph = 0; ph < 2; ++ph) {
    __syncthreads();
    for (int ch = 0; ch < 8; ++ch) {
      int q = t + 256 * ch;            // [0,2048) float4 slots
      ((float4*)Ws)[q] = ((const float4*)(W + (size_t)ph * 64 * D))[q];
    }
    __syncthreads();
    for (int kk = 0; kk < 16; ++kk) {
      float4 a4[4];
#pragma unroll
      for (int r = 0; r < 4; ++r)
        a4[r] = vld[r] ? ((const float4*)(h + (size_t)gi[r] * D))[ph * 16 + kk]
                       : make_float4(0.f, 0.f, 0.f, 0.f);
      float4 b0[4], b1[4];
#pragma unroll
      for (int k = 0; k < 4; ++k) {
        b0[k] = ((const float4*)(Ws + (kk * 4 + k) * D))[tx];
        b1[k] = ((const float4*)(Ws + (kk * 4 + k) * D))[16 + tx];
      }
#pragma unroll
      for (int r = 0; r < 4; ++r) {
        float4 a = a4[r];
#pragma unroll
        for (int c = 0; c < 4; ++c) {
          acc[r][c] += a.x * (&b0[0].x)[c] + a.y * (&b0[1].x)[c] +
                       a.z * (&b0[2].x)[c] + a.w * (&b0[3].x)[c];
          acc[r][4 + c] += a.x * (&b1[0].x)[c] + a.y * (&b1[1].x)[c] +
                           a.z * (&b1[2].x)[c] + a.w * (&b1[3].x)[c];
        }
      }
    }
  }
#pragma unroll
  for (int r = 0; r < 4; ++r) {
    if (vld[r]) {
      ((float4*)(S + (size_t)gi[r] * D))[tx] =
          make_float4(acc[r][0], acc[r][1], acc[r][2], acc[r][3]);
      ((float4*)(S + (size_t)gi[r] * D))[16 + tx] =
          make_float4(acc[r][4], acc[r][5], acc[r][6], acc[r][7]);
    }
  }
}

// ---------- fused: drop-mask + aggregate + self + bias + LN/ReLU or log_softmax
// One 32-lane group per node (8 nodes/block): ballot-compact surviving edges
// into LDS, then gather s[c] rows 8-in-flight. No __syncthreads.
// att_rev: when rev[p] >= 0, simS[rev[p]] == simS[p] bitwise -> reuse sm.
template <int MODE>
__global__ __launch_bounds__(256) void k_combine(
    const float* __restrict__ s, const float* __restrict__ simS,
    const float* __restrict__ rsE, const int* __restrict__ rev,
    const int* __restrict__ rptr, const int* __restrict__ colS,
    const float* __restrict__ bias, const float* __restrict__ g,
    const float* __restrict__ be, const float* __restrict__ dWp,
    const float* __restrict__ dbp, float* __restrict__ outF,
    float* __restrict__ nrmOut, int N) {
  __shared__ float wL[8 * 32];
  __shared__ int cLd[8 * 32];
  int grp = threadIdx.x >> 5, sub = threadIdx.x & 31;
  int half = grp & 1;
  int i = blockIdx.x * 8 + grp;
  if (i >= N) return;
  int gb = grp * 32;
  float w0 = dWp[0], w1 = dWp[1], bd = dbp[0];
  int p0 = rptr[i], p1 = rptr[i + 1];
  float ri = rsE[i];
  float4 acc = make_float4(0.f, 0.f, 0.f, 0.f);
  int deg = 0;
  for (int base = p0; base < p1; base += 32) {
    int p = base + sub;
    bool inr = p < p1;
    float sm = inr ? simS[p] : 0.f;
    int c = inr ? colS[p] : 0;
    int rv = inr ? rev[p] : -1;
    bool keep = false;
    float a = 0.f;
    if (sm != 0.f) {
      a = sm / ri;
      float ar = (rv >= 0) ? sm / rsE[c] : 0.f;
      float x = a * w0 + ar * w1 + bd;
      float sc = (x >= 0.f) ? 1.f / (1.f + expf(-x)) : expf(x) / (1.f + expf(x));
      keep = sc > 0.5f;
    }
    unsigned long long mb = __ballot(keep);
    unsigned mh = (unsigned)(mb >> (half * 32));
    int pos = __popc(mh & ((1u << sub) - 1u));
    int K = __popc(mh);
    if (keep) {
      wL[gb + pos] = expf(a);
      cLd[gb + pos] = c;
    }
    __builtin_amdgcn_wave_barrier();
    deg += K;
    for (int j0 = 0; j0 < K; j0 += 8) {
      int cc_[8];
      float ww[8];
      float4 b[8];
#pragma unroll
      for (int k = 0; k < 8; ++k) {
        int idx = j0 + k;
        bool vv = idx < K;
        cc_[k] = vv ? cLd[gb + idx] : i;
        ww[k] = vv ? wL[gb + idx] : 0.f;
      }
#pragma unroll
      for (int k = 0; k < 8; ++k)
        b[k] = ((const float4*)(s + (size_t)cc_[k] * D))[sub];
#pragma unroll
      for (int k = 0; k < 8; ++k) {
        acc.x += ww[k] * b[k].x; acc.y += ww[k] * b[k].y;
        acc.z += ww[k] * b[k].z; acc.w += ww[k] * b[k].w;
      }
    }
    __builtin_amdgcn_wave_barrier();   // wL/cLd reused next chunk
  }
  // per-group epilogue: all 32 lanes of this node
  float wd = expf(1.0f / (float)(deg + 1));
  float4 sv = ((const float4*)(s + (size_t)i * D))[sub];
  float4 bb = ((const float4*)bias)[sub];
  float4 v = make_float4(acc.x + wd * sv.x + bb.x, acc.y + wd * sv.y + bb.y,
                         acc.z + wd * sv.z + bb.z, acc.w + wd * sv.w + bb.w);
  if (MODE == 0) {
    float sm = v.x + v.y + v.z + v.w;
    for (int off = 16; off > 0; off >>= 1) sm += __shfl_down(sm, off, 32);
    float mu = __shfl(sm, 0, 32) * (1.f / 128.f);
    float4 dv = make_float4(v.x - mu, v.y - mu, v.z - mu, v.w - mu);
    float q = dv.x * dv.x + dv.y * dv.y + dv.z * dv.z + dv.w * dv.w;
    for (int off = 16; off > 0; off >>= 1) q += __shfl_down(q, off, 32);
    float var = __shfl(q, 0, 32) * (1.f / 128.f);
    float rstd = rsqrtf(var + EPS);
    float4 gg = ((const float4*)g)[sub];
    float4 eb = ((const float4*)be)[sub];
    float4 y = make_float4(fmaxf(dv.x * rstd * gg.x + eb.x, 0.f),
                           fmaxf(dv.y * rstd * gg.y + eb.y, 0.f),
                           fmaxf(dv.z * rstd * gg.z + eb.z, 0.f),
                           fmaxf(dv.w * rstd * gg.w + eb.w, 0.f));
    ((float4*)(outF + (size_t)i * D))[sub] = y;
    float q2 = y.x * y.x + y.y * y.y + y.z * y.z + y.w * y.w;
    for (int off = 16; off > 0; off >>= 1) q2 += __shfl_down(q2, off, 32);
    if (sub == 0) nrmOut[i] = sqrtf(q2);
  } else {
    float mx = fmaxf(fmaxf(v.x, v.y), fmaxf(v.z, v.w));
    for (int off = 16; off > 0; off >>= 1) mx = fmaxf(mx, __shfl_down(mx, off, 32));
    float m = __shfl(mx, 0, 32);
    float es = expf(v.x - m) + expf(v.y - m) + expf(v.z - m) + expf(v.w - m);
    for (int off = 16; off > 0; off >>= 1) es += __shfl_down(es, off, 32);
    float l = logf(__shfl(es, 0, 32)) + m;
    ((float4*)(outF + (size_t)i * D))[sub] =
        make_float4(v.x - l, v.y - l, v.z - l, v.w - l);
  }
}

extern "C" void kernel_launch(void* const* d_in, const int* in_sizes, int n_in,
                              void* d_out, int out_size, void* d_ws, size_t ws_size,
                              hipStream_t stream) {
  const float* x   = (const float*)d_in[0];
  const float* W0  = (const float*)d_in[1];
  const float* b0  = (const float*)d_in[2];
  const float* W1  = (const float*)d_in[3];
  const float* b1  = (const float*)d_in[4];
  const float* g1  = (const float*)d_in[5];
  const float* be1 = (const float*)d_in[6];
  const float* g2  = (const float*)d_in[7];
  const float* be2 = (const float*)d_in[8];
  const float* dW  = (const float*)d_in[9];
  const float* db  = (const float*)d_in[10];
  const int* row   = (const int*)d_in[11];
  const int* col   = (const int*)d_in[12];
  int N = in_sizes[0] / D;
  int E = in_sizes[11];
  float* out = (float*)d_out;

  float* base = (float*)d_ws;
  size_t off = 0;
  auto alloc = [&](size_t elems) {
    float* p = base + off;
    off += (elems + 3) & ~(size_t)3;
    return p;
  };
  size_t N128 = (size_t)N * D;
  int nb = (N + 1023) / 1024;          // scan chunks (1024 counts each)
  int NpadS = nb * 1024;               // cnt region covers int4 tail reads
  float* hA   = alloc(N128);
  float* hB   = alloc(N128);
  float* s    = alloc(N128);
  int*   colS = (int*)alloc(E);
  int*   rev  = (int*)alloc(E);
  float* simS = alloc(E);
  unsigned* pairs = (unsigned*)alloc(E);
  int*   cc   = (int*)alloc((size_t)2 * NpadS);  // cnt | bcur (zeroed together)
  int*   cnt  = cc;
  int*   bcur = cc + NpadS;            // ceil(N/4) counters used
  int*   rptr = (int*)alloc(N + 1);
  float* rsE  = alloc(N);
  float* nrm  = alloc(N);
  (void)ws_size; (void)n_in; (void)out_size;

  int cB = (E + 255) / 256;
  int nB = (N + 7) / 8;
  int nG = (N + 63) / 64;
  int nSim = (N + 7) / 8;
  int nRs = (N + 255) / 256;
  int nC = (N + 7) / 8;
  int NBKT = (N + 127) / 128;

  hipMemsetAsync(cc, 0, (size_t)2 * NpadS * sizeof(int), stream);
  k_pre<<<cB + nB, 256, 0, stream>>>(row, cnt, E, x, nrm, N, cB);
  k_scan<<<1, 256, 0, stream>>>(cnt, rptr, N, E, nb * 4);
  k_bktA<<<cB, 256, 0, stream>>>(row, col, rptr, bcur, pairs, E);
  k_bktB<<<NBKT, 256, 0, stream>>>(pairs, rptr, colS, N);
  k_rev<<<nSim, 256, 0, stream>>>(colS, rptr, rev, N);

  auto layer = [&](const float* hin, float* hout, const float* Wf,
                   const float* bf, const float* gf, const float* bef,
                   float* nrmOut, int mode) {
    k_sim<<<nSim, 256, 0, stream>>>(hin, nrm, rptr, colS, rev, simS, N);
    k_gemmrs<<<nG + nRs, 256, 0, stream>>>(hin, Wf, s, simS, rptr, rsE, N, nG);
    if (mode == 0)
      k_combine<0><<<nC, 256, 0, stream>>>(s, simS, rsE, rev, rptr, colS, bf, gf,
                                           bef, dW, db, hout, nrmOut, N);
    else
      k_combine<1><<<nC, 256, 0, stream>>>(s, simS, rsE, rev, rptr, colS, bf, gf,
                                           bef, dW, db, hout, nullptr, N);
  };
  // layer 0: x -> hA (W0, b0, ln1); writes nrm of hA
  layer(x, hA, W0, b0, g1, be1, nrm, 0);
  // layer 1: hA -> hB (W1, b1, ln2); writes nrm of hB
  layer(hA, hB, W1, b1, g2, be2, nrm, 0);
  // final: hB -> out (W1, b1, log_softmax)  [source bug reuses convs[-2]]
  layer(hB, out, W1, b1, nullptr, nullptr, nullptr, 1);
}

// Round 10
// 607.796 us; speedup vs baseline: 1.0549x; 1.0549x over previous
//
#include <hip/hip_runtime.h>
#include <hip/hip_bf16.h>

#define D 128
#define EPS 1e-5f
#define SCAP 32   // per-group compaction chunk in k_sim

// ---------- fused: edge count (atomics) + input-x row norms ----------
__global__ __launch_bounds__(256) void k_pre(
    const int* __restrict__ row, int* __restrict__ cnt, int E,
    const float* __restrict__ h, float* __restrict__ nrm, int N, int cB) {
  if ((int)blockIdx.x < cB) {
    int e = blockIdx.x * 256 + threadIdx.x;
    if (e < E) atomicAdd(&cnt[row[e]], 1);
  } else {
    int i = (blockIdx.x - cB) * 8 + (threadIdx.x >> 5);
    int sub = threadIdx.x & 31;
    if (i >= N) return;
    float4 a = ((const float4*)(h + (size_t)i * D))[sub];
    float v = a.x * a.x + a.y * a.y + a.z * a.z + a.w * a.w;
    for (int off = 16; off > 0; off >>= 1) v += __shfl_down(v, off, 32);
    if (sub == 0) nrm[i] = sqrtf(v);
  }
}

// ---------- two-level scan: bsum -> bscan -> apply ----------
__global__ __launch_bounds__(256) void k_bsum(const int* __restrict__ cnt,
                                              int* __restrict__ bsum) {
  int t = threadIdx.x;
  int base = blockIdx.x * 1024 + t * 4;
  int4 c4 = ((const int4*)(cnt + base))[0];
  int s = c4.x + c4.y + c4.z + c4.w;
  for (int off = 32; off > 0; off >>= 1) s += __shfl_down(s, off);
  __shared__ int sh[4];
  if ((t & 63) == 0) sh[t >> 6] = s;
  __syncthreads();
  if (t == 0) bsum[blockIdx.x] = sh[0] + sh[1] + sh[2] + sh[3];
}

__global__ __launch_bounds__(256) void k_bscan(const int* __restrict__ bsum,
                                               int* __restrict__ boff, int nb,
                                               int* __restrict__ rptr, int N, int E) {
  __shared__ int sh[256];
  int t = threadIdx.x;
  int v = (t < nb) ? bsum[t] : 0;
  sh[t] = v;
  __syncthreads();
  for (int off = 1; off < 256; off <<= 1) {
    int u = (t >= off) ? sh[t - off] : 0;
    __syncthreads();
    sh[t] += u;
    __syncthreads();
  }
  if (t < nb) boff[t] = sh[t] - v;     // exclusive
  if (t == 0) rptr[N] = E;
}

__global__ __launch_bounds__(256) void k_apply(const int* __restrict__ cnt,
                                               const int* __restrict__ boff,
                                               int* __restrict__ rptr, int N) {
  __shared__ int sh[256];
  int t = threadIdx.x;
  int base = blockIdx.x * 1024 + t * 4;
  int4 c4 = ((const int4*)(cnt + base))[0];
  int e1 = c4.x, e2 = c4.x + c4.y, e3 = c4.x + c4.y + c4.z;
  int tot = e3 + c4.w;
  sh[t] = tot;
  __syncthreads();
  for (int off = 1; off < 256; off <<= 1) {
    int u = (t >= off) ? sh[t - off] : 0;
    __syncthreads();
    sh[t] += u;
    __syncthreads();
  }
  int o = sh[t] - tot + boff[blockIdx.x];
  if (base + 0 < N) rptr[base + 0] = o;
  if (base + 1 < N) rptr[base + 1] = o + e1;
  if (base + 2 < N) rptr[base + 2] = o + e2;
  if (base + 3 < N) rptr[base + 3] = o + e3;
}

// colS only: one random 4B store per edge (rowS removed -> half the
// write-allocate traffic; row index is implicit in node-centric consumers).
__global__ __launch_bounds__(256) void k_scatter(
    const int* __restrict__ row, const int* __restrict__ col,
    const int* __restrict__ rptr, int* __restrict__ cur,
    int* __restrict__ colS, int E) {
  int e = blockIdx.x * 256 + threadIdx.x;
  if (e < E) {
    int r = row[e];
    int p = rptr[r] + atomicAdd(&cur[r], 1);
    colS[p] = col[e];
  }
}

// node-centric reverse-edge lookup: group of 32 lanes per node i; lane's
// edge p -> search i in c's adjacency list.
__global__ __launch_bounds__(256) void k_rev(const int* __restrict__ colS,
                                             const int* __restrict__ rptr,
                                             int* __restrict__ rev, int N) {
  int grp = threadIdx.x >> 5, sub = threadIdx.x & 31;
  int i = blockIdx.x * 8 + grp;
  if (i >= N) return;
  int p0 = rptr[i], p1 = rptr[i + 1];
  for (int p = p0 + sub; p < p1; p += 32) {
    int c = colS[p];
    int q1 = rptr[c + 1];
    int rv = -1;
    for (int q = rptr[c]; q < q1; ++q)
      if (colS[q] == i) { rv = q; break; }
    rev[p] = rv;
  }
}

// ---------- sim: one dot per undirected pair; owner rule handles truncation.
// Node i computes edge p=(i->c) iff (c > i) || (rev[p] < 0). When rev exists
// the bitwise-identical value is scattered to both directions.
__global__ __launch_bounds__(256) void k_sim(
    const float* __restrict__ h, const float* __restrict__ nrm,
    const int* __restrict__ rptr, const int* __restrict__ colS,
    const int* __restrict__ rev, float* __restrict__ simS, int N) {
  __shared__ int cL[8 * SCAP];
  __shared__ int pL[8 * SCAP];
  __shared__ int rL[8 * SCAP];
  __shared__ float nL[8 * SCAP];
  int grp = threadIdx.x >> 5;          // 8 groups of 32 lanes
  int sub = threadIdx.x & 31;
  int half = grp & 1;                  // lane 0-31 vs 32-63 within wave64
  int i = blockIdx.x * 8 + grp;
  if (i >= N) return;
  int gb = grp * SCAP;
  int p0 = rptr[i], p1 = rptr[i + 1];
  float4 ai = ((const float4*)(h + (size_t)i * D))[sub];
  float ni = nrm[i];
  for (int base = p0; base < p1; base += SCAP) {
    int p = base + sub;
    bool inr = p < p1;
    int c = inr ? colS[p] : 0;
    int rv = inr ? rev[p] : 0;
    bool ok = inr && (c > i || rv < 0);   // ownership rule
    unsigned long long mb = __ballot(ok);
    unsigned mh = (unsigned)(mb >> (half * 32));
    int pos = __popc(mh & ((1u << sub) - 1u));
    int K = __popc(mh);
    if (ok) {
      cL[gb + pos] = c;
      pL[gb + pos] = p;
      rL[gb + pos] = rv;
      nL[gb + pos] = nrm[c];
    }
    __builtin_amdgcn_wave_barrier();
    for (int j0 = 0; j0 < K; j0 += 8) {
      int cc_[8];
      bool vv[8];
      float4 b[8];
#pragma unroll
      for (int k = 0; k < 8; ++k) {
        int idx = j0 + k;
        vv[k] = idx < K;
        cc_[k] = vv[k] ? cL[gb + idx] : i;
      }
#pragma unroll
      for (int k = 0; k < 8; ++k)
        b[k] = ((const float4*)(h + (size_t)cc_[k] * D))[sub];
#pragma unroll
      for (int k = 0; k < 8; ++k) {
        float v = ai.x * b[k].x + ai.y * b[k].y + ai.z * b[k].z + ai.w * b[k].w;
        for (int off = 16; off > 0; off >>= 1) v += __shfl_down(v, off, 32);
        if (sub == 0 && vv[k]) {
          int idx = j0 + k;
          float sm = v / (ni * nL[gb + idx]);
          sm = (sm < 0.1f) ? 0.0f : sm;
          simS[pL[gb + idx]] = sm;       // this direction
          int rv2 = rL[gb + idx];
          if (rv2 >= 0) simS[rv2] = sm;  // reverse direction (bitwise equal)
        }
      }
    }
    __builtin_amdgcn_wave_barrier();   // LDS reused next chunk
  }
}

// ---------- row l1 norms of thresholded sims (tiny, sequential) ----------
__global__ __launch_bounds__(256) void k_rs(const float* __restrict__ simS,
                                            const int* __restrict__ rptr,
                                            float* __restrict__ rsE, int N) {
  int i = blockIdx.x * 256 + threadIdx.x;
  if (i >= N) return;
  int p1 = rptr[i + 1];
  float rs = 0.f;
  for (int p = rptr[i]; p < p1; ++p) rs += simS[p];
  rsE[i] = (rs > 0.f) ? rs : 1.f;
}

// ---------- s = h @ W (f32, BM=64, 256 thr, 4x8/thread, Ws-only LDS) ----------
__global__ __launch_bounds__(256) void k_gemm(const float* __restrict__ h,
                                              const float* __restrict__ W,
                                              float* __restrict__ S, int N) {
  __shared__ float Ws[64 * D];         // 32 KB (one K-phase of W)
  int t = threadIdx.x;
  int i0 = blockIdx.x * 64;
  int tx = t & 15, ty = t >> 4;        // rows 4ty..4ty+3, cols 4tx & 64+4tx
  int gi[4];
  bool vld[4];
#pragma unroll
  for (int r = 0; r < 4; ++r) {
    gi[r] = i0 + ty * 4 + r;
    vld[r] = gi[r] < N;
  }
  float acc[4][8] = {};
  for (int ph = 0; ph < 2; ++ph) {
    __syncthreads();
    for (int ch = 0; ch < 8; ++ch) {
      int q = t + 256 * ch;            // [0,2048) float4 slots
      ((float4*)Ws)[q] = ((const float4*)(W + (size_t)ph * 64 * D))[q];
    }
    __syncthreads();
    for (int kk = 0; kk < 16; ++kk) {
      float4 a4[4];
#pragma unroll
      for (int r = 0; r < 4; ++r)
        a4[r] = vld[r] ? ((const float4*)(h + (size_t)gi[r] * D))[ph * 16 + kk]
                       : make_float4(0.f, 0.f, 0.f, 0.f);
      float4 b0[4], b1[4];
#pragma unroll
      for (int k = 0; k < 4; ++k) {
        b0[k] = ((const float4*)(Ws + (kk * 4 + k) * D))[tx];
        b1[k] = ((const float4*)(Ws + (kk * 4 + k) * D))[16 + tx];
      }
#pragma unroll
      for (int r = 0; r < 4; ++r) {
        float4 a = a4[r];
#pragma unroll
        for (int c = 0; c < 4; ++c) {
          acc[r][c] += a.x * (&b0[0].x)[c] + a.y * (&b0[1].x)[c] +
                       a.z * (&b0[2].x)[c] + a.w * (&b0[3].x)[c];
          acc[r][4 + c] += a.x * (&b1[0].x)[c] + a.y * (&b1[1].x)[c] +
                           a.z * (&b1[2].x)[c] + a.w * (&b1[3].x)[c];
        }
      }
    }
  }
#pragma unroll
  for (int r = 0; r < 4; ++r) {
    if (vld[r]) {
      ((float4*)(S + (size_t)gi[r] * D))[tx] =
          make_float4(acc[r][0], acc[r][1], acc[r][2], acc[r][3]);
      ((float4*)(S + (size_t)gi[r] * D))[16 + tx] =
          make_float4(acc[r][4], acc[r][5], acc[r][6], acc[r][7]);
    }
  }
}

// ---------- fused: drop-mask + aggregate + self + bias + LN/ReLU or log_softmax
// One 32-lane group per node (8 nodes/block): ballot-compact surviving edges
// into LDS, then gather s[c] rows 8-in-flight. No __syncthreads.
// att_rev: when rev[p] >= 0, simS[rev[p]] == simS[p] bitwise -> reuse sm.
template <int MODE>
__global__ __launch_bounds__(256) void k_combine(
    const float* __restrict__ s, const float* __restrict__ simS,
    const float* __restrict__ rsE, const int* __restrict__ rev,
    const int* __restrict__ rptr, const int* __restrict__ colS,
    const float* __restrict__ bias, const float* __restrict__ g,
    const float* __restrict__ be, const float* __restrict__ dWp,
    const float* __restrict__ dbp, float* __restrict__ outF,
    float* __restrict__ nrmOut, int N) {
  __shared__ float wL[8 * 32];
  __shared__ int cLd[8 * 32];
  int grp = threadIdx.x >> 5, sub = threadIdx.x & 31;
  int half = grp & 1;
  int i = blockIdx.x * 8 + grp;
  if (i >= N) return;
  int gb = grp * 32;
  float w0 = dWp[0], w1 = dWp[1], bd = dbp[0];
  int p0 = rptr[i], p1 = rptr[i + 1];
  float ri = rsE[i];
  float4 acc = make_float4(0.f, 0.f, 0.f, 0.f);
  int deg = 0;
  for (int base = p0; base < p1; base += 32) {
    int p = base + sub;
    bool inr = p < p1;
    float sm = inr ? simS[p] : 0.f;
    int c = inr ? colS[p] : 0;
    int rv = inr ? rev[p] : -1;
    bool keep = false;
    float a = 0.f;
    if (sm != 0.f) {
      a = sm / ri;
      float ar = (rv >= 0) ? sm / rsE[c] : 0.f;
      float x = a * w0 + ar * w1 + bd;
      float sc = (x >= 0.f) ? 1.f / (1.f + expf(-x)) : expf(x) / (1.f + expf(x));
      keep = sc > 0.5f;
    }
    unsigned long long mb = __ballot(keep);
    unsigned mh = (unsigned)(mb >> (half * 32));
    int pos = __popc(mh & ((1u << sub) - 1u));
    int K = __popc(mh);
    if (keep) {
      wL[gb + pos] = expf(a);
      cLd[gb + pos] = c;
    }
    __builtin_amdgcn_wave_barrier();
    deg += K;
    for (int j0 = 0; j0 < K; j0 += 8) {
      int cc_[8];
      float ww[8];
      float4 b[8];
#pragma unroll
      for (int k = 0; k < 8; ++k) {
        int idx = j0 + k;
        bool vv = idx < K;
        cc_[k] = vv ? cLd[gb + idx] : i;
        ww[k] = vv ? wL[gb + idx] : 0.f;
      }
#pragma unroll
      for (int k = 0; k < 8; ++k)
        b[k] = ((const float4*)(s + (size_t)cc_[k] * D))[sub];
#pragma unroll
      for (int k = 0; k < 8; ++k) {
        acc.x += ww[k] * b[k].x; acc.y += ww[k] * b[k].y;
        acc.z += ww[k] * b[k].z; acc.w += ww[k] * b[k].w;
      }
    }
    __builtin_amdgcn_wave_barrier();   // wL/cLd reused next chunk
  }
  // per-group epilogue: all 32 lanes of this node
  float wd = expf(1.0f / (float)(deg + 1));
  float4 sv = ((const float4*)(s + (size_t)i * D))[sub];
  float4 bb = ((const float4*)bias)[sub];
  float4 v = make_float4(acc.x + wd * sv.x + bb.x, acc.y + wd * sv.y + bb.y,
                         acc.z + wd * sv.z + bb.z, acc.w + wd * sv.w + bb.w);
  if (MODE == 0) {
    float sm = v.x + v.y + v.z + v.w;
    for (int off = 16; off > 0; off >>= 1) sm += __shfl_down(sm, off, 32);
    float mu = __shfl(sm, 0, 32) * (1.f / 128.f);
    float4 dv = make_float4(v.x - mu, v.y - mu, v.z - mu, v.w - mu);
    float q = dv.x * dv.x + dv.y * dv.y + dv.z * dv.z + dv.w * dv.w;
    for (int off = 16; off > 0; off >>= 1) q += __shfl_down(q, off, 32);
    float var = __shfl(q, 0, 32) * (1.f / 128.f);
    float rstd = rsqrtf(var + EPS);
    float4 gg = ((const float4*)g)[sub];
    float4 eb = ((const float4*)be)[sub];
    float4 y = make_float4(fmaxf(dv.x * rstd * gg.x + eb.x, 0.f),
                           fmaxf(dv.y * rstd * gg.y + eb.y, 0.f),
                           fmaxf(dv.z * rstd * gg.z + eb.z, 0.f),
                           fmaxf(dv.w * rstd * gg.w + eb.w, 0.f));
    ((float4*)(outF + (size_t)i * D))[sub] = y;
    float q2 = y.x * y.x + y.y * y.y + y.z * y.z + y.w * y.w;
    for (int off = 16; off > 0; off >>= 1) q2 += __shfl_down(q2, off, 32);
    if (sub == 0) nrmOut[i] = sqrtf(q2);
  } else {
    float mx = fmaxf(fmaxf(v.x, v.y), fmaxf(v.z, v.w));
    for (int off = 16; off > 0; off >>= 1) mx = fmaxf(mx, __shfl_down(mx, off, 32));
    float m = __shfl(mx, 0, 32);
    float es = expf(v.x - m) + expf(v.y - m) + expf(v.z - m) + expf(v.w - m);
    for (int off = 16; off > 0; off >>= 1) es += __shfl_down(es, off, 32);
    float l = logf(__shfl(es, 0, 32)) + m;
    ((float4*)(outF + (size_t)i * D))[sub] =
        make_float4(v.x - l, v.y - l, v.z - l, v.w - l);
  }
}

extern "C" void kernel_launch(void* const* d_in, const int* in_sizes, int n_in,
                              void* d_out, int out_size, void* d_ws, size_t ws_size,
                              hipStream_t stream) {
  const float* x   = (const float*)d_in[0];
  const float* W0  = (const float*)d_in[1];
  const float* b0  = (const float*)d_in[2];
  const float* W1  = (const float*)d_in[3];
  const float* b1  = (const float*)d_in[4];
  const float* g1  = (const float*)d_in[5];
  const float* be1 = (const float*)d_in[6];
  const float* g2  = (const float*)d_in[7];
  const float* be2 = (const float*)d_in[8];
  const float* dW  = (const float*)d_in[9];
  const float* db  = (const float*)d_in[10];
  const int* row   = (const int*)d_in[11];
  const int* col   = (const int*)d_in[12];
  int N = in_sizes[0] / D;
  int E = in_sizes[11];
  float* out = (float*)d_out;

  float* base = (float*)d_ws;
  size_t off = 0;
  auto alloc = [&](size_t elems) {
    float* p = base + off;
    off += (elems + 3) & ~(size_t)3;
    return p;
  };
  size_t N128 = (size_t)N * D;
  int nb = (N + 1023) / 1024;          // scan blocks (1024 counts each)
  int NpadS = nb * 1024;               // cnt region covers int4 tail reads
  float* hA   = alloc(N128);
  float* hB   = alloc(N128);
  float* s    = alloc(N128);
  int*   colS = (int*)alloc(E);
  int*   rev  = (int*)alloc(E);
  float* simS = alloc(E);
  int*   cc   = (int*)alloc((size_t)2 * NpadS);  // cnt | cur (zeroed together)
  int*   cnt  = cc;
  int*   cur  = cc + NpadS;
  int*   rptr = (int*)alloc(N + 1);
  float* rsE  = alloc(N);
  float* nrm  = alloc(N);
  int*   bsum = (int*)alloc(nb);
  int*   boff = (int*)alloc(nb);
  (void)ws_size; (void)n_in; (void)out_size;

  int cB = (E + 255) / 256;
  int nB = (N + 7) / 8;
  int nG = (N + 63) / 64;
  int nSim = (N + 7) / 8;
  int nRs = (N + 255) / 256;
  int nC = (N + 7) / 8;

  hipMemsetAsync(cc, 0, (size_t)2 * NpadS * sizeof(int), stream);
  k_pre<<<cB + nB, 256, 0, stream>>>(row, cnt, E, x, nrm, N, cB);
  k_bsum<<<nb, 256, 0, stream>>>(cnt, bsum);
  k_bscan<<<1, 256, 0, stream>>>(bsum, boff, nb, rptr, N, E);
  k_apply<<<nb, 256, 0, stream>>>(cnt, boff, rptr, N);
  k_scatter<<<cB, 256, 0, stream>>>(row, col, rptr, cur, colS, E);
  k_rev<<<nSim, 256, 0, stream>>>(colS, rptr, rev, N);

  auto layer = [&](const float* hin, float* hout, const float* Wf,
                   const float* bf, const float* gf, const float* bef,
                   float* nrmOut, int mode) {
    k_sim<<<nSim, 256, 0, stream>>>(hin, nrm, rptr, colS, rev, simS, N);
    k_rs<<<nRs, 256, 0, stream>>>(simS, rptr, rsE, N);
    k_gemm<<<nG, 256, 0, stream>>>(hin, Wf, s, N);
    if (mode == 0)
      k_combine<0><<<nC, 256, 0, stream>>>(s, simS, rsE, rev, rptr, colS, bf, gf,
                                           bef, dW, db, hout, nrmOut, N);
    else
      k_combine<1><<<nC, 256, 0, stream>>>(s, simS, rsE, rev, rptr, colS, bf, gf,
                                           bef, dW, db, hout, nullptr, N);
  };
  // layer 0: x -> hA (W0, b0, ln1); writes nrm of hA
  layer(x, hA, W0, b0, g1, be1, nrm, 0);
  // layer 1: hA -> hB (W1, b1, ln2); writes nrm of hB
  layer(hA, hB, W1, b1, g2, be2, nrm, 0);
  // final: hB -> out (W1, b1, log_softmax)  [source bug reuses convs[-2]]
  layer(hB, out, W1, b1, nullptr, nullptr, nullptr, 1);
}

// Round 11
// 573.777 us; speedup vs baseline: 1.1174x; 1.0593x over previous
//
#include <hip/hip_runtime.h>
#include <hip/hip_bf16.h>

#define D 128
#define EPS 1e-5f
#define SCAP 32   // per-group compaction chunk in k_sim

// ---------- fused: edge count (atomics, saving slot) + input-x row norms ----
// slot[e] = atomicAdd return = within-row slot index; coalesced 4B store.
// This lets k_scatter run atomic-free (device-scope atomics write through
// to HBM ~64B/op -> the old scatter's 55MB WRITE_SIZE).
__global__ __launch_bounds__(256) void k_pre(
    const int* __restrict__ row, int* __restrict__ cnt, int* __restrict__ slot,
    int E, const float* __restrict__ h, float* __restrict__ nrm, int N, int cB) {
  if ((int)blockIdx.x < cB) {
    int e = blockIdx.x * 256 + threadIdx.x;
    if (e < E) slot[e] = atomicAdd(&cnt[row[e]], 1);
  } else {
    int i = (blockIdx.x - cB) * 8 + (threadIdx.x >> 5);
    int sub = threadIdx.x & 31;
    if (i >= N) return;
    float4 a = ((const float4*)(h + (size_t)i * D))[sub];
    float v = a.x * a.x + a.y * a.y + a.z * a.z + a.w * a.w;
    for (int off = 16; off > 0; off >>= 1) v += __shfl_down(v, off, 32);
    if (sub == 0) nrm[i] = sqrtf(v);
  }
}

// ---------- two-level scan: bsum -> bscan -> apply ----------
__global__ __launch_bounds__(256) void k_bsum(const int* __restrict__ cnt,
                                              int* __restrict__ bsum) {
  int t = threadIdx.x;
  int base = blockIdx.x * 1024 + t * 4;
  int4 c4 = ((const int4*)(cnt + base))[0];
  int s = c4.x + c4.y + c4.z + c4.w;
  for (int off = 32; off > 0; off >>= 1) s += __shfl_down(s, off);
  __shared__ int sh[4];
  if ((t & 63) == 0) sh[t >> 6] = s;
  __syncthreads();
  if (t == 0) bsum[blockIdx.x] = sh[0] + sh[1] + sh[2] + sh[3];
}

__global__ __launch_bounds__(256) void k_bscan(const int* __restrict__ bsum,
                                               int* __restrict__ boff, int nb,
                                               int* __restrict__ rptr, int N, int E) {
  __shared__ int sh[256];
  int t = threadIdx.x;
  int v = (t < nb) ? bsum[t] : 0;
  sh[t] = v;
  __syncthreads();
  for (int off = 1; off < 256; off <<= 1) {
    int u = (t >= off) ? sh[t - off] : 0;
    __syncthreads();
    sh[t] += u;
    __syncthreads();
  }
  if (t < nb) boff[t] = sh[t] - v;     // exclusive
  if (t == 0) rptr[N] = E;
}

__global__ __launch_bounds__(256) void k_apply(const int* __restrict__ cnt,
                                               const int* __restrict__ boff,
                                               int* __restrict__ rptr, int N) {
  __shared__ int sh[256];
  int t = threadIdx.x;
  int base = blockIdx.x * 1024 + t * 4;
  int4 c4 = ((const int4*)(cnt + base))[0];
  int e1 = c4.x, e2 = c4.x + c4.y, e3 = c4.x + c4.y + c4.z;
  int tot = e3 + c4.w;
  sh[t] = tot;
  __syncthreads();
  for (int off = 1; off < 256; off <<= 1) {
    int u = (t >= off) ? sh[t - off] : 0;
    __syncthreads();
    sh[t] += u;
    __syncthreads();
  }
  int o = sh[t] - tot + boff[blockIdx.x];
  if (base + 0 < N) rptr[base + 0] = o;
  if (base + 1 < N) rptr[base + 1] = o + e1;
  if (base + 2 < N) rptr[base + 2] = o + e2;
  if (base + 3 < N) rptr[base + 3] = o + e3;
}

// atomic-free scatter: p = rptr[r] + slot[e]; colS stores are independent
// random 4B stores into an L2-resident 3.2MB window (no write-through).
__global__ __launch_bounds__(256) void k_scatter(
    const int* __restrict__ row, const int* __restrict__ col,
    const int* __restrict__ rptr, const int* __restrict__ slot,
    int* __restrict__ colS, int E) {
  int e = blockIdx.x * 256 + threadIdx.x;
  if (e < E) {
    int r = row[e];
    int p = rptr[r] + slot[e];
    colS[p] = col[e];
  }
}

// node-centric reverse-edge lookup: group of 32 lanes per node i; lane's
// edge p -> search i in c's adjacency list.
__global__ __launch_bounds__(256) void k_rev(const int* __restrict__ colS,
                                             const int* __restrict__ rptr,
                                             int* __restrict__ rev, int N) {
  int grp = threadIdx.x >> 5, sub = threadIdx.x & 31;
  int i = blockIdx.x * 8 + grp;
  if (i >= N) return;
  int p0 = rptr[i], p1 = rptr[i + 1];
  for (int p = p0 + sub; p < p1; p += 32) {
    int c = colS[p];
    int q1 = rptr[c + 1];
    int rv = -1;
    for (int q = rptr[c]; q < q1; ++q)
      if (colS[q] == i) { rv = q; break; }
    rev[p] = rv;
  }
}

// ---------- sim: one dot per undirected pair; owner rule handles truncation.
// Node i computes edge p=(i->c) iff (c > i) || (rev[p] < 0). When rev exists
// the bitwise-identical value is scattered to both directions.
__global__ __launch_bounds__(256) void k_sim(
    const float* __restrict__ h, const float* __restrict__ nrm,
    const int* __restrict__ rptr, const int* __restrict__ colS,
    const int* __restrict__ rev, float* __restrict__ simS, int N) {
  __shared__ int cL[8 * SCAP];
  __shared__ int pL[8 * SCAP];
  __shared__ int rL[8 * SCAP];
  __shared__ float nL[8 * SCAP];
  int grp = threadIdx.x >> 5;          // 8 groups of 32 lanes
  int sub = threadIdx.x & 31;
  int half = grp & 1;                  // lane 0-31 vs 32-63 within wave64
  int i = blockIdx.x * 8 + grp;
  if (i >= N) return;
  int gb = grp * SCAP;
  int p0 = rptr[i], p1 = rptr[i + 1];
  float4 ai = ((const float4*)(h + (size_t)i * D))[sub];
  float ni = nrm[i];
  for (int base = p0; base < p1; base += SCAP) {
    int p = base + sub;
    bool inr = p < p1;
    int c = inr ? colS[p] : 0;
    int rv = inr ? rev[p] : 0;
    bool ok = inr && (c > i || rv < 0);   // ownership rule
    unsigned long long mb = __ballot(ok);
    unsigned mh = (unsigned)(mb >> (half * 32));
    int pos = __popc(mh & ((1u << sub) - 1u));
    int K = __popc(mh);
    if (ok) {
      cL[gb + pos] = c;
      pL[gb + pos] = p;
      rL[gb + pos] = rv;
      nL[gb + pos] = nrm[c];
    }
    __builtin_amdgcn_wave_barrier();
    for (int j0 = 0; j0 < K; j0 += 8) {
      int cc_[8];
      bool vv[8];
      float4 b[8];
#pragma unroll
      for (int k = 0; k < 8; ++k) {
        int idx = j0 + k;
        vv[k] = idx < K;
        cc_[k] = vv[k] ? cL[gb + idx] : i;
      }
#pragma unroll
      for (int k = 0; k < 8; ++k)
        b[k] = ((const float4*)(h + (size_t)cc_[k] * D))[sub];
#pragma unroll
      for (int k = 0; k < 8; ++k) {
        float v = ai.x * b[k].x + ai.y * b[k].y + ai.z * b[k].z + ai.w * b[k].w;
        for (int off = 16; off > 0; off >>= 1) v += __shfl_down(v, off, 32);
        if (sub == 0 && vv[k]) {
          int idx = j0 + k;
          float sm = v / (ni * nL[gb + idx]);
          sm = (sm < 0.1f) ? 0.0f : sm;
          simS[pL[gb + idx]] = sm;       // this direction
          int rv2 = rL[gb + idx];
          if (rv2 >= 0) simS[rv2] = sm;  // reverse direction (bitwise equal)
        }
      }
    }
    __builtin_amdgcn_wave_barrier();   // LDS reused next chunk
  }
}

// ---------- row l1 norms of thresholded sims (tiny, sequential) ----------
__global__ __launch_bounds__(256) void k_rs(const float* __restrict__ simS,
                                            const int* __restrict__ rptr,
                                            float* __restrict__ rsE, int N) {
  int i = blockIdx.x * 256 + threadIdx.x;
  if (i >= N) return;
  int p1 = rptr[i + 1];
  float rs = 0.f;
  for (int p = rptr[i]; p < p1; ++p) rs += simS[p];
  rsE[i] = (rs > 0.f) ? rs : 1.f;
}

// ---------- s = h @ W (f32, BM=64, 256 thr, 4x8/thread, Ws-only LDS) ----------
__global__ __launch_bounds__(256) void k_gemm(const float* __restrict__ h,
                                              const float* __restrict__ W,
                                              float* __restrict__ S, int N) {
  __shared__ float Ws[64 * D];         // 32 KB (one K-phase of W)
  int t = threadIdx.x;
  int i0 = blockIdx.x * 64;
  int tx = t & 15, ty = t >> 4;        // rows 4ty..4ty+3, cols 4tx & 64+4tx
  int gi[4];
  bool vld[4];
#pragma unroll
  for (int r = 0; r < 4; ++r) {
    gi[r] = i0 + ty * 4 + r;
    vld[r] = gi[r] < N;
  }
  float acc[4][8] = {};
  for (int ph = 0; ph < 2; ++ph) {
    __syncthreads();
    for (int ch = 0; ch < 8; ++ch) {
      int q = t + 256 * ch;            // [0,2048) float4 slots
      ((float4*)Ws)[q] = ((const float4*)(W + (size_t)ph * 64 * D))[q];
    }
    __syncthreads();
    for (int kk = 0; kk < 16; ++kk) {
      float4 a4[4];
#pragma unroll
      for (int r = 0; r < 4; ++r)
        a4[r] = vld[r] ? ((const float4*)(h + (size_t)gi[r] * D))[ph * 16 + kk]
                       : make_float4(0.f, 0.f, 0.f, 0.f);
      float4 b0[4], b1[4];
#pragma unroll
      for (int k = 0; k < 4; ++k) {
        b0[k] = ((const float4*)(Ws + (kk * 4 + k) * D))[tx];
        b1[k] = ((const float4*)(Ws + (kk * 4 + k) * D))[16 + tx];
      }
#pragma unroll
      for (int r = 0; r < 4; ++r) {
        float4 a = a4[r];
#pragma unroll
        for (int c = 0; c < 4; ++c) {
          acc[r][c] += a.x * (&b0[0].x)[c] + a.y * (&b0[1].x)[c] +
                       a.z * (&b0[2].x)[c] + a.w * (&b0[3].x)[c];
          acc[r][4 + c] += a.x * (&b1[0].x)[c] + a.y * (&b1[1].x)[c] +
                           a.z * (&b1[2].x)[c] + a.w * (&b1[3].x)[c];
        }
      }
    }
  }
#pragma unroll
  for (int r = 0; r < 4; ++r) {
    if (vld[r]) {
      ((float4*)(S + (size_t)gi[r] * D))[tx] =
          make_float4(acc[r][0], acc[r][1], acc[r][2], acc[r][3]);
      ((float4*)(S + (size_t)gi[r] * D))[16 + tx] =
          make_float4(acc[r][4], acc[r][5], acc[r][6], acc[r][7]);
    }
  }
}

// ---------- fused: drop-mask + aggregate + self + bias + LN/ReLU or log_softmax
// One 32-lane group per node (8 nodes/block): ballot-compact surviving edges
// into LDS, then gather s[c] rows 8-in-flight. No __syncthreads.
// att_rev: when rev[p] >= 0, simS[rev[p]] == simS[p] bitwise -> reuse sm.
template <int MODE>
__global__ __launch_bounds__(256) void k_combine(
    const float* __restrict__ s, const float* __restrict__ simS,
    const float* __restrict__ rsE, const int* __restrict__ rev,
    const int* __restrict__ rptr, const int* __restrict__ colS,
    const float* __restrict__ bias, const float* __restrict__ g,
    const float* __restrict__ be, const float* __restrict__ dWp,
    const float* __restrict__ dbp, float* __restrict__ outF,
    float* __restrict__ nrmOut, int N) {
  __shared__ float wL[8 * 32];
  __shared__ int cLd[8 * 32];
  int grp = threadIdx.x >> 5, sub = threadIdx.x & 31;
  int half = grp & 1;
  int i = blockIdx.x * 8 + grp;
  if (i >= N) return;
  int gb = grp * 32;
  float w0 = dWp[0], w1 = dWp[1], bd = dbp[0];
  int p0 = rptr[i], p1 = rptr[i + 1];
  float ri = rsE[i];
  float4 acc = make_float4(0.f, 0.f, 0.f, 0.f);
  int deg = 0;
  for (int base = p0; base < p1; base += 32) {
    int p = base + sub;
    bool inr = p < p1;
    float sm = inr ? simS[p] : 0.f;
    int c = inr ? colS[p] : 0;
    int rv = inr ? rev[p] : -1;
    bool keep = false;
    float a = 0.f;
    if (sm != 0.f) {
      a = sm / ri;
      float ar = (rv >= 0) ? sm / rsE[c] : 0.f;
      float x = a * w0 + ar * w1 + bd;
      float sc = (x >= 0.f) ? 1.f / (1.f + expf(-x)) : expf(x) / (1.f + expf(x));
      keep = sc > 0.5f;
    }
    unsigned long long mb = __ballot(keep);
    unsigned mh = (unsigned)(mb >> (half * 32));
    int pos = __popc(mh & ((1u << sub) - 1u));
    int K = __popc(mh);
    if (keep) {
      wL[gb + pos] = expf(a);
      cLd[gb + pos] = c;
    }
    __builtin_amdgcn_wave_barrier();
    deg += K;
    for (int j0 = 0; j0 < K; j0 += 8) {
      int cc_[8];
      float ww[8];
      float4 b[8];
#pragma unroll
      for (int k = 0; k < 8; ++k) {
        int idx = j0 + k;
        bool vv = idx < K;
        cc_[k] = vv ? cLd[gb + idx] : i;
        ww[k] = vv ? wL[gb + idx] : 0.f;
      }
#pragma unroll
      for (int k = 0; k < 8; ++k)
        b[k] = ((const float4*)(s + (size_t)cc_[k] * D))[sub];
#pragma unroll
      for (int k = 0; k < 8; ++k) {
        acc.x += ww[k] * b[k].x; acc.y += ww[k] * b[k].y;
        acc.z += ww[k] * b[k].z; acc.w += ww[k] * b[k].w;
      }
    }
    __builtin_amdgcn_wave_barrier();   // wL/cLd reused next chunk
  }
  // per-group epilogue: all 32 lanes of this node
  float wd = expf(1.0f / (float)(deg + 1));
  float4 sv = ((const float4*)(s + (size_t)i * D))[sub];
  float4 bb = ((const float4*)bias)[sub];
  float4 v = make_float4(acc.x + wd * sv.x + bb.x, acc.y + wd * sv.y + bb.y,
                         acc.z + wd * sv.z + bb.z, acc.w + wd * sv.w + bb.w);
  if (MODE == 0) {
    float sm = v.x + v.y + v.z + v.w;
    for (int off = 16; off > 0; off >>= 1) sm += __shfl_down(sm, off, 32);
    float mu = __shfl(sm, 0, 32) * (1.f / 128.f);
    float4 dv = make_float4(v.x - mu, v.y - mu, v.z - mu, v.w - mu);
    float q = dv.x * dv.x + dv.y * dv.y + dv.z * dv.z + dv.w * dv.w;
    for (int off = 16; off > 0; off >>= 1) q += __shfl_down(q, off, 32);
    float var = __shfl(q, 0, 32) * (1.f / 128.f);
    float rstd = rsqrtf(var + EPS);
    float4 gg = ((const float4*)g)[sub];
    float4 eb = ((const float4*)be)[sub];
    float4 y = make_float4(fmaxf(dv.x * rstd * gg.x + eb.x, 0.f),
                           fmaxf(dv.y * rstd * gg.y + eb.y, 0.f),
                           fmaxf(dv.z * rstd * gg.z + eb.z, 0.f),
                           fmaxf(dv.w * rstd * gg.w + eb.w, 0.f));
    ((float4*)(outF + (size_t)i * D))[sub] = y;
    float q2 = y.x * y.x + y.y * y.y + y.z * y.z + y.w * y.w;
    for (int off = 16; off > 0; off >>= 1) q2 += __shfl_down(q2, off, 32);
    if (sub == 0) nrmOut[i] = sqrtf(q2);
  } else {
    float mx = fmaxf(fmaxf(v.x, v.y), fmaxf(v.z, v.w));
    for (int off = 16; off > 0; off >>= 1) mx = fmaxf(mx, __shfl_down(mx, off, 32));
    float m = __shfl(mx, 0, 32);
    float es = expf(v.x - m) + expf(v.y - m) + expf(v.z - m) + expf(v.w - m);
    for (int off = 16; off > 0; off >>= 1) es += __shfl_down(es, off, 32);
    float l = logf(__shfl(es, 0, 32)) + m;
    ((float4*)(outF + (size_t)i * D))[sub] =
        make_float4(v.x - l, v.y - l, v.z - l, v.w - l);
  }
}

extern "C" void kernel_launch(void* const* d_in, const int* in_sizes, int n_in,
                              void* d_out, int out_size, void* d_ws, size_t ws_size,
                              hipStream_t stream) {
  const float* x   = (const float*)d_in[0];
  const float* W0  = (const float*)d_in[1];
  const float* b0  = (const float*)d_in[2];
  const float* W1  = (const float*)d_in[3];
  const float* b1  = (const float*)d_in[4];
  const float* g1  = (const float*)d_in[5];
  const float* be1 = (const float*)d_in[6];
  const float* g2  = (const float*)d_in[7];
  const float* be2 = (const float*)d_in[8];
  const float* dW  = (const float*)d_in[9];
  const float* db  = (const float*)d_in[10];
  const int* row   = (const int*)d_in[11];
  const int* col   = (const int*)d_in[12];
  int N = in_sizes[0] / D;
  int E = in_sizes[11];
  float* out = (float*)d_out;

  float* base = (float*)d_ws;
  size_t off = 0;
  auto alloc = [&](size_t elems) {
    float* p = base + off;
    off += (elems + 3) & ~(size_t)3;
    return p;
  };
  size_t N128 = (size_t)N * D;
  int nb = (N + 1023) / 1024;          // scan blocks (1024 counts each)
  int NpadS = nb * 1024;               // cnt region covers int4 tail reads
  float* hA   = alloc(N128);
  float* hB   = alloc(N128);
  float* s    = alloc(N128);
  int*   colS = (int*)alloc(E);
  int*   rev  = (int*)alloc(E);
  float* simS = alloc(E);
  int*   slot = (int*)alloc(E);
  int*   cnt  = (int*)alloc(NpadS);    // zeroed each launch
  int*   rptr = (int*)alloc(N + 1);
  float* rsE  = alloc(N);
  float* nrm  = alloc(N);
  int*   bsum = (int*)alloc(nb);
  int*   boff = (int*)alloc(nb);
  (void)ws_size; (void)n_in; (void)out_size;

  int cB = (E + 255) / 256;
  int nB = (N + 7) / 8;
  int nG = (N + 63) / 64;
  int nSim = (N + 7) / 8;
  int nRs = (N + 255) / 256;
  int nC = (N + 7) / 8;

  hipMemsetAsync(cnt, 0, (size_t)NpadS * sizeof(int), stream);
  k_pre<<<cB + nB, 256, 0, stream>>>(row, cnt, slot, E, x, nrm, N, cB);
  k_bsum<<<nb, 256, 0, stream>>>(cnt, bsum);
  k_bscan<<<1, 256, 0, stream>>>(bsum, boff, nb, rptr, N, E);
  k_apply<<<nb, 256, 0, stream>>>(cnt, boff, rptr, N);
  k_scatter<<<cB, 256, 0, stream>>>(row, col, rptr, slot, colS, E);
  k_rev<<<nSim, 256, 0, stream>>>(colS, rptr, rev, N);

  auto layer = [&](const float* hin, float* hout, const float* Wf,
                   const float* bf, const float* gf, const float* bef,
                   float* nrmOut, int mode) {
    k_sim<<<nSim, 256, 0, stream>>>(hin, nrm, rptr, colS, rev, simS, N);
    k_rs<<<nRs, 256, 0, stream>>>(simS, rptr, rsE, N);
    k_gemm<<<nG, 256, 0, stream>>>(hin, Wf, s, N);
    if (mode == 0)
      k_combine<0><<<nC, 256, 0, stream>>>(s, simS, rsE, rev, rptr, colS, bf, gf,
                                           bef, dW, db, hout, nrmOut, N);
    else
      k_combine<1><<<nC, 256, 0, stream>>>(s, simS, rsE, rev, rptr, colS, bf, gf,
                                           bef, dW, db, hout, nullptr, N);
  };
  // layer 0: x -> hA (W0, b0, ln1); writes nrm of hA
  layer(x, hA, W0, b0, g1, be1, nrm, 0);
  // layer 1: hA -> hB (W1, b1, ln2); writes nrm of hB
  layer(hA, hB, W1, b1, g2, be2, nrm, 0);
  // final: hB -> out (W1, b1, log_softmax)  [source bug reuses convs[-2]]
  layer(hB, out, W1, b1, nullptr, nullptr, nullptr, 1);
}